// Round 2
// baseline (260.644 us; speedup 1.0000x reference)
//
#include <hip/hip_runtime.h>

// WeatherLSTM round 7: 2-blocks-per-CU version (8 samples/block).
//  - grid 512 x 512 thr (8 waves); each CU hosts TWO blocks with
//    INDEPENDENT barriers -> when block A stalls on its per-iter
//    dependency chain (ds_read -> MFMA chain -> act chain -> barrier),
//    block B's waves issue. R6 counters: VALUBusy 51%, MfmaUtil 19%,
//    Occupancy 22.5% (1 block/CU) -> pure latency/barrier bound.
//  - B-frag cols 8..15 READ THE SAME LDS ADDRESSES as cols 0..7
//    (broadcast pairs, conflict-free), so MFMA C cols 8..15 duplicate
//    cols 0..7. Thread (col,quad) activates tile sel=col>>3 via 4
//    v_cndmask per layer: acts = 2/thread -> per-CU VALU/trans issue
//    identical to R6 (2 blocks x 2 acts == 1 block x 4 acts).
//  - Each wave owns units w*8..w*8+7 (two 16-row A-tiles); lane does
//    1 lstm_act per layer for unit w*8+sel*4+quad, sample col&7.
//  - Iteration k computes L0(k) and L1(k-1) with ONE barrier (R4 scheme):
//      reads  {H0 buf kbn = h0(k-1), H1 buf kb = h1(k-2), x(k)}
//      writes {H0 buf kb = h0(k),   H1 buf kbn = h1(k-1)}   (disjoint)
//  - x table [169][8][8 halves] = 21.6KB LDS, built once (row 168 zeros).
//  - Acts: weights prescaled log2e (2log2e for g); shared-rcp with fused
//    i*tanh(g) = B*D*(Eg-1)*R. 7 trans + ~16 VALU per act.
//  - MFMA layouts per m89/m91/m120 (verified R2-R6: absmax 4.9e-4).

typedef _Float16 h8 __attribute__((ext_vector_type(8)));
typedef _Float16 h4 __attribute__((ext_vector_type(4)));
typedef float f4 __attribute__((ext_vector_type(4)));

#define ROWB 208
#define HBUF (8 * ROWB)           // 1664 B per h buffer
#define XTAB_OFF 0
#define XTAB_BYTES (169 * 128)    // 21632 B (row 168 = zero pad)
#define H0_OFF XTAB_BYTES
#define H1_OFF (H0_OFF + 2 * HBUF)
#define SMEM_TOTAL (H1_OFF + 2 * HBUF)   // 28288 B -> 2 blocks/CU

#define K1F 1.4426950408889634f   // log2(e)
#define K2F 2.8853900817779268f   // 2*log2(e)

__device__ __forceinline__ float exp2_(float x) {
#if __has_builtin(__builtin_amdgcn_exp2f)
  return __builtin_amdgcn_exp2f(x);
#else
  float r; asm("v_exp_f32 %0, %1" : "=v"(r) : "v"(x)); return r;
#endif
}
__device__ __forceinline__ float rcp_(float x) {
#if __has_builtin(__builtin_amdgcn_rcpf)
  return __builtin_amdgcn_rcpf(x);
#else
  float r; asm("v_rcp_f32 %0, %1" : "=v"(r) : "v"(x)); return r;
#endif
}

__device__ __forceinline__ f4 mfma16(h8 a, h8 b, f4 c) {
  return __builtin_amdgcn_mfma_f32_16x16x32_f16(a, b, c, 0, 0, 0);
}

__device__ __forceinline__ h8 load_w8s(const float* __restrict__ p, float sc) {
  h8 r;
#pragma unroll
  for (int j = 0; j < 8; j++) r[j] = (_Float16)(p[j] * sc);
  return r;
}

// static per-component select (no runtime-indexed arrays -> no scratch)
__device__ __forceinline__ f4 sel4(int hi, f4 a, f4 b) {
  f4 r;
#pragma unroll
  for (int j = 0; j < 4; j++) r[j] = hi ? b[j] : a[j];
  return r;
}

// a[0]=i,a[1]=f,a[3]=o prescaled K1F; a[2]=g prescaled K2F.
// sigm(i)*tanh(g) = (Eg-1)/(A*C) = B*D*(Eg-1)*R with R=1/(ABCD).
__device__ __forceinline__ void lstm_act(f4 a, float& c, float& h) {
  float Ei = exp2_(-a[0]);
  float Ef = exp2_(-a[1]);
  float Eg = exp2_(a[2]);
  float Eo = exp2_(-a[3]);
  float A = 1.f + Ei, B = 1.f + Ef, C = 1.f + Eg, D = 1.f + Eo;
  float AB = A * B, CD = C * D, BD = B * D;
  float R  = rcp_(AB * CD);
  float fv = (A * CD) * R;               // sigm(f)
  float ig = (BD * (Eg - 1.f)) * R;      // sigm(i)*tanh(g)
  float ov = (AB * C) * R;               // sigm(o)
  c = fv * c + ig;
  float r2 = rcp_(exp2_(c * K2F) + 1.f);
  h = ov * (1.f - 2.f * r2);
}

extern "C" __global__ void __launch_bounds__(512, 4)
weather_lstm_mfma7(const float* __restrict__ x,
                   const float* __restrict__ Wih0, const float* __restrict__ Whh0,
                   const float* __restrict__ bih0, const float* __restrict__ bhh0,
                   const float* __restrict__ Wih1, const float* __restrict__ Whh1,
                   const float* __restrict__ bih1, const float* __restrict__ bhh1,
                   const float* __restrict__ W1, const float* __restrict__ b1,
                   const float* __restrict__ W2, const float* __restrict__ b2,
                   float* __restrict__ out)
{
  __shared__ __align__(16) unsigned char smem[SMEM_TOTAL];
  const int tid  = threadIdx.x;
  const int lane = tid & 63;
  const int w    = tid >> 6;      // wave 0..7 -> units w*8..w*8+7
  const int col  = lane & 15;     // MFMA col (sample = col&7, dup pair)
  const int s    = col & 7;       // real sample index within block
  const int sel  = col >> 3;      // which tile this thread activates
  const int quad = lane >> 4;     // 0..3
  const int sB   = blockIdx.x * 8;

  // ---- A-frag row decode: m = lane&15 = ul*4 + g; unit = w*8 + t*4 + ul ----
  const int g_  = col & 3;
  const int ul_ = col >> 2;
  const float asc = (g_ == 2) ? K2F : K1F;

  // ---- load + prescale weight A-frags (once), 2 tiles ----
  h8 a0[2][3], a1i[2][2], a1h[2][2];
#pragma unroll
  for (int t = 0; t < 2; t++) {
    const int r = g_ * 64 + w * 8 + t * 4 + ul_;
#pragma unroll
    for (int f = 0; f < 2; f++) {
      a0[t][f]  = load_w8s(Whh0 + r * 64 + f * 32 + quad * 8, asc);
      a1i[t][f] = load_w8s(Wih1 + r * 64 + f * 32 + quad * 8, asc);
      a1h[t][f] = load_w8s(Whh1 + r * 64 + f * 32 + quad * 8, asc);
    }
    h8 xw = {};
    if (quad == 0) {
#pragma unroll
      for (int j = 0; j < 4; j++) xw[j] = (_Float16)(Wih0[r * 4 + j] * asc);
    }
    a0[t][2] = xw;
  }

  // ---- biases (prescaled): lane C rows reg -> gate reg, unit w*8+t*4+quad ----
  f4 bias0v[2], bias1v[2];
#pragma unroll
  for (int t = 0; t < 2; t++) {
#pragma unroll
    for (int reg = 0; reg < 4; reg++) {
      const int rr = reg * 64 + w * 8 + t * 4 + quad;
      const float bs = (reg == 2) ? K2F : K1F;
      bias0v[t][reg] = (bih0[rr] + bhh0[rr]) * bs;
      bias1v[t][reg] = (bih1[rr] + bhh1[rr]) * bs;
    }
  }

  // ---- zero LDS, build x table ----
  for (int idx = tid; idx < SMEM_TOTAL / 4; idx += 512) ((int*)smem)[idx] = 0;
  __syncthreads();
  for (int idx = tid; idx < 8 * 168; idx += 512) {
    const int c_ = idx / 168, t_ = idx - c_ * 168;
    f4 xv = *(const f4*)(x + ((size_t)(sB + c_) * 168 + t_) * 4);
    h4 xh;
#pragma unroll
    for (int j = 0; j < 4; j++) xh[j] = (_Float16)xv[j];
    *(h4*)(smem + XTAB_OFF + t_ * 128 + c_ * 16) = xh;
  }
  __syncthreads();

  float c0 = 0.f, c1 = 0.f, hl = 0.f;
  const int bo = s * ROWB + quad * 16;                     // B-frag byte offset
  const int wo = s * ROWB + (w * 8 + sel * 4 + quad) * 2;  // h-write byte offset
  const unsigned char* xp = smem + XTAB_OFF + s * 16;

  for (int k = 0; k <= 168; k++) {
    const int kb = k & 1, kbn = kb ^ 1;
    const unsigned char* h0r = smem + H0_OFF + kbn * HBUF;  // h0(k-1)
    unsigned char*       h0w = smem + H0_OFF + kb  * HBUF;  // h0(k)
    const unsigned char* h1r = smem + H1_OFF + kb  * HBUF;  // h1(k-2)
    unsigned char*       h1w = smem + H1_OFF + kbn * HBUF;  // h1(k-1)

    // ---- shared ds_reads (cols c and c+8 read SAME addr -> broadcast) ----
    h8 b0  = *(const h8*)(h0r + bo);         // h0(k-1) k 0..31
    h8 b1v = *(const h8*)(h0r + bo + 64);    // h0(k-1) k 32..63
    h8 bx  = *(const h8*)(xp + k * 128);     // x(k) (quad0 data; others A=0)
    h8 q0  = *(const h8*)(h1r + bo);         // h1(k-2) k 0..31
    h8 q1  = *(const h8*)(h1r + bo + 64);    // h1(k-2) k 32..63

    // ---- 14 MFMAs, 4 independent chains ----
    f4 A[2], C[2];
#pragma unroll
    for (int t = 0; t < 2; t++) {
      A[t] = mfma16(a0[t][0], b0, bias0v[t]);       // L0 tile t
      C[t] = mfma16(a1i[t][0], b0, bias1v[t]);      // L1 tile t
      A[t] = mfma16(a0[t][1], b1v, A[t]);
      C[t] = mfma16(a1i[t][1], b1v, C[t]);
      A[t] = mfma16(a0[t][2], bx, A[t]);
      C[t] = mfma16(a1h[t][0], q0, C[t]);
      C[t] = mfma16(a1h[t][1], q1, C[t]);
    }

    // cols 8..15 hold duplicates of cols 0..7 -> thread acts on tile sel.
    // ---- L0 activation (discard at k==168) ----
    if (k < 168) {
      f4 G = sel4(sel, A[0], A[1]);
      float h0o;
      lstm_act(G, c0, h0o);
      *(_Float16*)(h0w + wo) = (_Float16)h0o;
    }
    // ---- L1 activation (discard at k==0) ----
    if (k > 0) {
      f4 G = sel4(sel, C[0], C[1]);
      lstm_act(G, c1, hl);
      *(_Float16*)(h1w + wo) = (_Float16)hl;
    }
    __syncthreads();
  }

  // ---------- MLP head (x table region dead; overlay) ----------
  float* fh = (float*)smem;              // [8][64] final h2, fp32
  fh[s * 64 + (w * 8 + sel * 4 + quad)] = hl;
  __syncthreads();

  {
    const int u = tid & 63, grp = tid >> 6;  // 8 grps x 1 sample
    float za = b1[u];
    const float* w1r = W1 + u * 64;
    const float* f0 = fh + grp * 64;
    for (int j = 0; j < 64; j++) za += w1r[j] * f0[j];
    float* zl = (float*)(smem + 4096);     // [8][64]
    zl[grp * 64 + u] = fmaxf(za, 0.f);
  }
  __syncthreads();

  if (tid < 96) {
    const float* zl = (const float*)(smem + 4096);
    const int s2 = tid / 12, o = tid - s2 * 12;
    float a = b2[o];
    for (int j = 0; j < 64; j++) a += W2[o * 64 + j] * zl[s2 * 64 + j];
    out[(sB + s2) * 12 + o] = a;
  }
}

extern "C" void kernel_launch(void* const* d_in, const int* in_sizes, int n_in,
                              void* d_out, int out_size, void* d_ws, size_t ws_size,
                              hipStream_t stream) {
  (void)in_sizes; (void)n_in; (void)d_ws; (void)ws_size; (void)out_size;
  const float* x    = (const float*)d_in[0];
  const float* Wih0 = (const float*)d_in[1];
  const float* Whh0 = (const float*)d_in[2];
  const float* bih0 = (const float*)d_in[3];
  const float* bhh0 = (const float*)d_in[4];
  const float* Wih1 = (const float*)d_in[5];
  const float* Whh1 = (const float*)d_in[6];
  const float* bih1 = (const float*)d_in[7];
  const float* bhh1 = (const float*)d_in[8];
  const float* W1   = (const float*)d_in[9];
  const float* b1   = (const float*)d_in[10];
  const float* W2   = (const float*)d_in[11];
  const float* b2   = (const float*)d_in[12];

  weather_lstm_mfma7<<<dim3(512), dim3(512), 0, stream>>>(
      x, Wih0, Whh0, bih0, bhh0, Wih1, Whh1, bih1, bhh1, W1, b1, W2, b2,
      (float*)d_out);
}

// Round 3
// 251.861 us; speedup vs baseline: 1.0349x; 1.0349x over previous
//
#include <hip/hip_runtime.h>

// WeatherLSTM round 8: wave-specialized desync version (no block barrier in loop).
//  - grid 256 x 512 thr (8 waves), 16 samples/block, 1 block/CU (R6 geometry).
//  - R6 post-mortem: 19% Mfma + 51% VALU, 30% idle -> the 8 waves were
//    BARRIER-PHASE-LOCKED (all MFMA together, all acts together, all wait).
//    R7 (2 blocks/CU) regressed: duplicated per-wave overhead + 2x MFMA.
//  - New: waves 0-3 compute L0 only (units w*16..+15, 4 gate-tiles,
//    12 MFMAs, 4 acts/thread); waves 4-7 compute L1 only (16 MFMAs,
//    4 acts/thread). SIMD s hosts L0-wave s and L1-wave s+4 -> the two
//    waves run OUT OF PHASE (L1 lags 1 step), so one wave's trans/VALU
//    act burst overlaps the other's MFMA + ds_read phase.
//  - Sync: per-wave monotone iteration counters in LDS (p0w[4], p1w[4]),
//    min-spin (volatile reads + s_sleep). h0 ring depth 4, h1 ring depth 2.
//      L0 iter k: spin min(p0w)>=k;  k>=4: spin min(p1w)>=k-3 (slot free)
//      L1 iter k: spin min(p1w)>=k;  spin min(p0w)>=k+1 (h0(k) ready)
//    Deadlock-free (lag analysis in journal); producers fence then bump.
//  - Gate-tiles are per-gate (tile g = gate g, 16 units) -> uniform
//    prescale per tile, acts gather G=(A0[j],A1[j],A2[j],A3[j]), h-writes
//    pack to one ds_write_b64 (4 consecutive units).
//  - x table [169][16][8 halves] = 43.3KB; total LDS 63.3KB.
//  - Acts: weights prescaled log2e (2log2e for g); shared-rcp with fused
//    i*tanh(g) = B*D*(Eg-1)*R. 7 trans + ~16 VALU per act.
//  - MFMA layouts per m89/m91/m120 (verified R2-R7: absmax 4.9e-4).

typedef _Float16 h8 __attribute__((ext_vector_type(8)));
typedef _Float16 h4 __attribute__((ext_vector_type(4)));
typedef float f4 __attribute__((ext_vector_type(4)));

#define ROWB 208
#define HBUF (16 * ROWB)              // 3328 B per h buffer
#define XTAB_OFF 0
#define XTAB_BYTES (169 * 256)        // 43264 B (row 168 = zero pad, unused now)
#define H0_OFF XTAB_BYTES             // ring of 4
#define H1_OFF (H0_OFF + 4 * HBUF)    // ring of 2
#define FLAG_OFF (H1_OFF + 2 * HBUF)  // p0w[4] @ +0, p1w[4] @ +16
#define SMEM_TOTAL (FLAG_OFF + 32)    // 63296 B

#define K1F 1.4426950408889634f   // log2(e)
#define K2F 2.8853900817779268f   // 2*log2(e)

__device__ __forceinline__ float exp2_(float x) {
#if __has_builtin(__builtin_amdgcn_exp2f)
  return __builtin_amdgcn_exp2f(x);
#else
  float r; asm("v_exp_f32 %0, %1" : "=v"(r) : "v"(x)); return r;
#endif
}
__device__ __forceinline__ float rcp_(float x) {
#if __has_builtin(__builtin_amdgcn_rcpf)
  return __builtin_amdgcn_rcpf(x);
#else
  float r; asm("v_rcp_f32 %0, %1" : "=v"(r) : "v"(x)); return r;
#endif
}

__device__ __forceinline__ f4 mfma16(h8 a, h8 b, f4 c) {
  return __builtin_amdgcn_mfma_f32_16x16x32_f16(a, b, c, 0, 0, 0);
}

__device__ __forceinline__ h8 load_w8s(const float* __restrict__ p, float sc) {
  h8 r;
#pragma unroll
  for (int j = 0; j < 8; j++) r[j] = (_Float16)(p[j] * sc);
  return r;
}

// spin until min(f[0..3]) >= target (monotone counters; all lanes broadcast-read)
__device__ __forceinline__ void spin_min_ge(volatile const int* f, int target) {
  for (;;) {
    int a = f[0], b = f[1], c = f[2], d = f[3];
    int m = min(min(a, b), min(c, d));
    if (m >= target) break;
    __builtin_amdgcn_s_sleep(1);
  }
}

// a[0]=i,a[1]=f,a[3]=o prescaled K1F; a[2]=g prescaled K2F.
// sigm(i)*tanh(g) = (Eg-1)/(A*C) = B*D*(Eg-1)*R with R=1/(ABCD).
__device__ __forceinline__ void lstm_act(f4 a, float& c, float& h) {
  float Ei = exp2_(-a[0]);
  float Ef = exp2_(-a[1]);
  float Eg = exp2_(a[2]);
  float Eo = exp2_(-a[3]);
  float A = 1.f + Ei, B = 1.f + Ef, C = 1.f + Eg, D = 1.f + Eo;
  float AB = A * B, CD = C * D, BD = B * D;
  float R  = rcp_(AB * CD);
  float fv = (A * CD) * R;               // sigm(f)
  float ig = (BD * (Eg - 1.f)) * R;      // sigm(i)*tanh(g)
  float ov = (AB * C) * R;               // sigm(o)
  c = fv * c + ig;
  float r2 = rcp_(exp2_(c * K2F) + 1.f);
  h = ov * (1.f - 2.f * r2);
}

extern "C" __global__ void __launch_bounds__(512, 2)
weather_lstm_mfma8(const float* __restrict__ x,
                   const float* __restrict__ Wih0, const float* __restrict__ Whh0,
                   const float* __restrict__ bih0, const float* __restrict__ bhh0,
                   const float* __restrict__ Wih1, const float* __restrict__ Whh1,
                   const float* __restrict__ bih1, const float* __restrict__ bhh1,
                   const float* __restrict__ W1, const float* __restrict__ b1,
                   const float* __restrict__ W2, const float* __restrict__ b2,
                   float* __restrict__ out)
{
  __shared__ __align__(16) unsigned char smem[SMEM_TOTAL];
  const int tid  = threadIdx.x;
  const int lane = tid & 63;
  const int w    = tid >> 6;      // 0..3 = L0 waves, 4..7 = L1 waves
  const int col  = lane & 15;     // sample index
  const int quad = lane >> 4;     // 0..3
  const int sB   = blockIdx.x * 16;

  volatile int* p0w = (volatile int*)(smem + FLAG_OFF);
  volatile int* p1w = (volatile int*)(smem + FLAG_OFF + 16);

  // ---- zero LDS, build x table ----
  for (int idx = tid; idx < SMEM_TOTAL / 4; idx += 512) ((int*)smem)[idx] = 0;
  __syncthreads();
  for (int idx = tid; idx < 16 * 168; idx += 512) {
    const int c_ = idx / 168, t_ = idx - c_ * 168;
    f4 xv = *(const f4*)(x + ((size_t)(sB + c_) * 168 + t_) * 4);
    h4 xh;
#pragma unroll
    for (int j = 0; j < 4; j++) xh[j] = (_Float16)xv[j];
    *(h4*)(smem + XTAB_OFF + t_ * 256 + c_ * 16) = xh;
  }
  __syncthreads();

  const int wl = w & 3;
  const int u0 = wl * 16;             // this wave's 16 units
  const int uu = u0 + quad * 4;       // first of 4 units this thread activates
  const int bo = col * ROWB + quad * 16;   // B-frag byte offset
  const int wo = col * ROWB + uu * 2;      // h-write byte offset (8B aligned)

  float hout[4] = {0.f, 0.f, 0.f, 0.f};    // final h2 (set by L1 waves)

  if (w < 4) {
    // ================= L0 waves =================
    h8 aW[4][2], aX[4];
    f4 bias[4];
#pragma unroll
    for (int g = 0; g < 4; ++g) {
      const float sc = (g == 2) ? K2F : K1F;
      const int r = g * 64 + u0 + col;      // A-frag row (gate g, unit u0+col)
#pragma unroll
      for (int f = 0; f < 2; ++f)
        aW[g][f] = load_w8s(Whh0 + r * 64 + f * 32 + quad * 8, sc);
      h8 xw = {};
      if (quad == 0) {
#pragma unroll
        for (int j = 0; j < 4; ++j) xw[j] = (_Float16)(Wih0[r * 4 + j] * sc);
      }
      aX[g] = xw;
#pragma unroll
      for (int j = 0; j < 4; ++j)
        bias[g][j] = (bih0[g * 64 + uu + j] + bhh0[g * 64 + uu + j]) * sc;
    }

    float cc[4] = {0.f, 0.f, 0.f, 0.f};
    const unsigned char* xp = smem + XTAB_OFF + col * 16;

    for (int k = 0; k < 168; ++k) {
      spin_min_ge(p0w, k);                      // others wrote h0(k-1)
      if (k >= 4) spin_min_ge(p1w, k - 3);      // L1 done with h0(k-4) slot

      const unsigned char* h0r = smem + H0_OFF + ((k - 1) & 3) * HBUF; // h0(k-1); k=0 -> slot3 zeros
      unsigned char*       h0wp = smem + H0_OFF + (k & 3) * HBUF;

      h8 b0  = *(const h8*)(h0r + bo);
      h8 b1v = *(const h8*)(h0r + bo + 64);
      h8 bx  = *(const h8*)(xp + k * 256);

      f4 A0 = mfma16(aW[0][0], b0, bias[0]);
      f4 A1 = mfma16(aW[1][0], b0, bias[1]);
      f4 A2 = mfma16(aW[2][0], b0, bias[2]);
      f4 A3 = mfma16(aW[3][0], b0, bias[3]);
      A0 = mfma16(aW[0][1], b1v, A0);
      A1 = mfma16(aW[1][1], b1v, A1);
      A2 = mfma16(aW[2][1], b1v, A2);
      A3 = mfma16(aW[3][1], b1v, A3);
      A0 = mfma16(aX[0], bx, A0);
      A1 = mfma16(aX[1], bx, A1);
      A2 = mfma16(aX[2], bx, A2);
      A3 = mfma16(aX[3], bx, A3);

      h4 hv;
#pragma unroll
      for (int j = 0; j < 4; ++j) {
        f4 G; G[0] = A0[j]; G[1] = A1[j]; G[2] = A2[j]; G[3] = A3[j];
        float ho;
        lstm_act(G, cc[j], ho);
        hv[j] = (_Float16)ho;
      }
      *(h4*)(h0wp + wo) = hv;

      __threadfence_block();
      if (lane == 0) p0w[wl] = k + 1;
    }
  } else {
    // ================= L1 waves =================
    h8 aI[4][2], aH[4][2];
    f4 bias[4];
#pragma unroll
    for (int g = 0; g < 4; ++g) {
      const float sc = (g == 2) ? K2F : K1F;
      const int r = g * 64 + u0 + col;
#pragma unroll
      for (int f = 0; f < 2; ++f) {
        aI[g][f] = load_w8s(Wih1 + r * 64 + f * 32 + quad * 8, sc);
        aH[g][f] = load_w8s(Whh1 + r * 64 + f * 32 + quad * 8, sc);
      }
#pragma unroll
      for (int j = 0; j < 4; ++j)
        bias[g][j] = (bih1[g * 64 + uu + j] + bhh1[g * 64 + uu + j]) * sc;
    }

    float cc[4] = {0.f, 0.f, 0.f, 0.f};

    for (int k = 0; k < 168; ++k) {
      spin_min_ge(p1w, k);                      // own group wrote h1(k-1)
      spin_min_ge(p0w, k + 1);                  // h0(k) ready

      const unsigned char* h0r  = smem + H0_OFF + (k & 3) * HBUF;        // h0(k)
      const unsigned char* h1r  = smem + H1_OFF + ((k - 1) & 1) * HBUF;  // h1(k-1); k=0 -> slot1 zeros
      unsigned char*       h1wp = smem + H1_OFF + (k & 1) * HBUF;

      h8 b0  = *(const h8*)(h0r + bo);
      h8 b1v = *(const h8*)(h0r + bo + 64);
      h8 q0  = *(const h8*)(h1r + bo);
      h8 q1  = *(const h8*)(h1r + bo + 64);

      f4 C0 = mfma16(aI[0][0], b0, bias[0]);
      f4 C1 = mfma16(aI[1][0], b0, bias[1]);
      f4 C2 = mfma16(aI[2][0], b0, bias[2]);
      f4 C3 = mfma16(aI[3][0], b0, bias[3]);
      C0 = mfma16(aI[0][1], b1v, C0);
      C1 = mfma16(aI[1][1], b1v, C1);
      C2 = mfma16(aI[2][1], b1v, C2);
      C3 = mfma16(aI[3][1], b1v, C3);
      C0 = mfma16(aH[0][0], q0, C0);
      C1 = mfma16(aH[1][0], q0, C1);
      C2 = mfma16(aH[2][0], q0, C2);
      C3 = mfma16(aH[3][0], q0, C3);
      C0 = mfma16(aH[0][1], q1, C0);
      C1 = mfma16(aH[1][1], q1, C1);
      C2 = mfma16(aH[2][1], q1, C2);
      C3 = mfma16(aH[3][1], q1, C3);

      h4 hv;
#pragma unroll
      for (int j = 0; j < 4; ++j) {
        f4 G; G[0] = C0[j]; G[1] = C1[j]; G[2] = C2[j]; G[3] = C3[j];
        lstm_act(G, cc[j], hout[j]);
        hv[j] = (_Float16)hout[j];
      }
      *(h4*)(h1wp + wo) = hv;

      __threadfence_block();
      if (lane == 0) p1w[wl] = k + 1;
    }
  }

  __syncthreads();

  // ---------- MLP head (x table region dead; overlay) ----------
  float* fh = (float*)smem;              // [16][64] final h2, fp32
  if (w >= 4) {
    f4 hv; hv[0] = hout[0]; hv[1] = hout[1]; hv[2] = hout[2]; hv[3] = hout[3];
    *(f4*)(fh + col * 64 + uu) = hv;
  }
  __syncthreads();

  {
    const int u = tid & 63, grp = tid >> 6;  // 8 grps x 2 samples
    const float* w1r = W1 + u * 64;
    float* zl = (float*)(smem + 4096);       // [16][64]
#pragma unroll
    for (int rep = 0; rep < 2; ++rep) {
      const int s2 = grp + rep * 8;
      float za = b1[u];
      const float* f0 = fh + s2 * 64;
      for (int j = 0; j < 64; ++j) za += w1r[j] * f0[j];
      zl[s2 * 64 + u] = fmaxf(za, 0.f);
    }
  }
  __syncthreads();

  if (tid < 192) {
    const float* zl = (const float*)(smem + 4096);
    const int s2 = tid / 12, o = tid - s2 * 12;
    float a = b2[o];
    for (int j = 0; j < 64; ++j) a += W2[o * 64 + j] * zl[s2 * 64 + j];
    out[(sB + s2) * 12 + o] = a;
  }
}

extern "C" void kernel_launch(void* const* d_in, const int* in_sizes, int n_in,
                              void* d_out, int out_size, void* d_ws, size_t ws_size,
                              hipStream_t stream) {
  (void)in_sizes; (void)n_in; (void)d_ws; (void)ws_size; (void)out_size;
  const float* x    = (const float*)d_in[0];
  const float* Wih0 = (const float*)d_in[1];
  const float* Whh0 = (const float*)d_in[2];
  const float* bih0 = (const float*)d_in[3];
  const float* bhh0 = (const float*)d_in[4];
  const float* Wih1 = (const float*)d_in[5];
  const float* Whh1 = (const float*)d_in[6];
  const float* bih1 = (const float*)d_in[7];
  const float* bhh1 = (const float*)d_in[8];
  const float* W1   = (const float*)d_in[9];
  const float* b1   = (const float*)d_in[10];
  const float* W2   = (const float*)d_in[11];
  const float* b2   = (const float*)d_in[12];

  weather_lstm_mfma8<<<dim3(256), dim3(512), 0, stream>>>(
      x, Wih0, Whh0, bih0, bhh0, Wih1, Whh1, bih1, bhh1, W1, b1, W2, b2,
      (float*)d_out);
}